// Round 4
// baseline (249.143 us; speedup 1.0000x reference)
//
#include <hip/hip_runtime.h>
#include <stdint.h>

typedef uint32_t u32;
using bf16x8 = __attribute__((ext_vector_type(8))) short;
using f32x4  = __attribute__((ext_vector_type(4))) float;

#define MFMA16(a, b, c) __builtin_amdgcn_mfma_f32_16x16x32_bf16((a), (b), (c), 0, 0, 0)

__device__ __forceinline__ unsigned short f2bf(float f) {
  u32 u = __builtin_bit_cast(u32, f);
  return (unsigned short)((u + 0x7FFFu + ((u >> 16) & 1u)) >> 16);  // RNE
}

__device__ __forceinline__ void gl_lds16(const unsigned short* g, unsigned short* l) {
  __builtin_amdgcn_global_load_lds((const __attribute__((address_space(1))) void*)g,
                                   (__attribute__((address_space(3))) void*)l, 16, 0, 0);
}

// ---------------- Threefry-2x32-20, key = (0, 42) ----------------
#define TFR(r) x0 += x1; x1 = (x1 << (r)) | (x1 >> (32 - (r))); x1 ^= x0;

__device__ __forceinline__ void threefry2x32(u32 i0, u32 i1, u32& o0, u32& o1) {
  const u32 ks0 = 0u, ks1 = 42u, ks2 = 0x1BD11BDAu ^ 42u;
  u32 x0 = i0 + ks0;
  u32 x1 = i1 + ks1;
  TFR(13) TFR(15) TFR(26) TFR(6)
  x0 += ks1; x1 += ks2 + 1u;
  TFR(17) TFR(29) TFR(16) TFR(24)
  x0 += ks2; x1 += ks0 + 2u;
  TFR(13) TFR(15) TFR(26) TFR(6)
  x0 += ks0; x1 += ks1 + 3u;
  TFR(17) TFR(29) TFR(16) TFR(24)
  x0 += ks1; x1 += ks2 + 4u;
  TFR(13) TFR(15) TFR(26) TFR(6)
  x0 += ks2; x1 += ks0 + 5u;
  o0 = x0; o1 = x1;
}

// partitionable-threefry mask bit for flat index j (shape [8,8,1024,1024], j < 2^26):
// counter = (hi=0, lo=j); 32-bit bits = o0 ^ o1; keep (mask=False) <=> MSB == 1.
__device__ __forceinline__ u32 keep_bit(u32 j) {
  u32 o0, o1;
  threefry2x32(0u, j, o0, o1);
  return (o0 ^ o1) >> 31;
}

// ---------------- fp32 -> bf16 conversion of x, qkv_w, proj_w ----------------
__global__ __launch_bounds__(256) void cvt_kernel(
    const float* __restrict__ x, const float* __restrict__ qw, const float* __restrict__ pw,
    unsigned short* __restrict__ xb, unsigned short* __restrict__ qwb,
    unsigned short* __restrict__ pwb) {
  int t = blockIdx.x * 256 + threadIdx.x;
  const float4* src; unsigned short* dst; int idx;
  if (t < 1048576)      { src = (const float4*)x;  dst = xb;  idx = t; }
  else if (t < 1245184) { src = (const float4*)qw; dst = qwb; idx = t - 1048576; }
  else                  { src = (const float4*)pw; dst = pwb; idx = t - 1245184; }
  float4 v = src[idx];
  ushort4 o = make_ushort4(f2bf(v.x), f2bf(v.y), f2bf(v.z), f2bf(v.w));
  ((ushort4*)dst)[idx] = o;
}

// ---------------- bf16 GEMM (m97 structure), C = A[M,512] * Bm[N,512]^T ----------
template<int EPI>
__global__ __launch_bounds__(256)
void gemm_kernel(const unsigned short* __restrict__ A, const unsigned short* __restrict__ Bm,
                 const float* __restrict__ bias, unsigned short* __restrict__ q_out,
                 unsigned short* __restrict__ k_out, unsigned short* __restrict__ vt_out,
                 float* __restrict__ f_out) {
  __shared__ __align__(16) unsigned short lA[128 * 32];
  __shared__ __align__(16) unsigned short lB[128 * 32];
  const int tid = threadIdx.x;
  const int lane = tid & 63, w = tid >> 6;
  const int hi = lane >> 4, lo = lane & 15;
  const int wm = w >> 1, wn = w & 1;
  const int m0 = blockIdx.y * 128, n0 = blockIdx.x * 128;
  const int srow = lane >> 2, skc = (lane & 3) * 8;

  f32x4 acc[4][4];
#pragma unroll
  for (int i = 0; i < 4; ++i)
#pragma unroll
    for (int j = 0; j < 4; ++j) acc[i][j] = (f32x4){0.f, 0.f, 0.f, 0.f};

  for (int kt = 0; kt < 16; ++kt) {
    const int k0 = kt * 32;
    __syncthreads();
#pragma unroll
    for (int c = 0; c < 2; ++c) {
      const int rr = (w * 2 + c) * 16 + srow;
      gl_lds16(A  + (size_t)(m0 + rr) * 512 + k0 + skc, &lA[(w * 2 + c) * 512]);
      gl_lds16(Bm + (size_t)(n0 + rr) * 512 + k0 + skc, &lB[(w * 2 + c) * 512]);
    }
    __syncthreads();

    bf16x8 af[4], bfr[4];
#pragma unroll
    for (int i = 0; i < 4; ++i) af[i]  = *(const bf16x8*)&lA[(wm * 64 + i * 16 + lo) * 32 + hi * 8];
#pragma unroll
    for (int i = 0; i < 4; ++i) bfr[i] = *(const bf16x8*)&lB[(wn * 64 + i * 16 + lo) * 32 + hi * 8];
#pragma unroll
    for (int i = 0; i < 4; ++i)
#pragma unroll
      for (int j = 0; j < 4; ++j)
        acc[i][j] = MFMA16(af[i], bfr[j], acc[i][j]);
  }

  // C/D layout: col = lane&15, row = (lane>>4)*4 + reg  (m89/m91)
#pragma unroll
  for (int i = 0; i < 4; ++i) {
    const int rowb = m0 + wm * 64 + i * 16 + hi * 4;
#pragma unroll
    for (int j = 0; j < 4; ++j) {
      const int col = n0 + wn * 64 + j * 16 + lo;
      const float bv = bias[col];
      if (EPI == 0) {
        const int which = col >> 9, hh = (col >> 6) & 7, dd = col & 63;
#pragma unroll
        for (int r = 0; r < 4; ++r) {
          const int tok = rowb + r;
          const int b = tok >> 10, nt = tok & 1023;
          const int bh = b * 8 + hh;
          const unsigned short val = f2bf(acc[i][j][r] + bv);
          if (which == 0)      q_out[((size_t)((bh << 10) + nt)) * 64 + dd] = val;
          else if (which == 1) k_out[((size_t)((bh << 10) + nt)) * 64 + dd] = val;
          else                 vt_out[((size_t)bh * 64 + dd) * 1024 + nt] = val;
        }
      } else {
#pragma unroll
        for (int r = 0; r < 4; ++r)
          f_out[(size_t)(rowb + r) * 512 + col] = acc[i][j][r] + bv;
      }
    }
  }
}

// ---------------- fused flash attention + partitionable-threefry mask ----------------
// Grid 1024 = bh(64) x qtile(16). Block = 4 waves; wave w owns 16 q-rows.
// Per 32-key iter: 8 threefry/lane for mask, QK^T MFMA, online softmax,
// P->LDS relayout, ones-MFMA row-sum, PV MFMA with transposed V.
__global__ __launch_bounds__(256) void attn_kernel(
    const unsigned short* __restrict__ Qb, const unsigned short* __restrict__ Kb,
    const unsigned short* __restrict__ VTb, unsigned short* __restrict__ aout) {
  __shared__ __align__(16) unsigned short plds[4][16 * 40];  // per-wave, 80B row stride
  const int tid = threadIdx.x;
  const int lane = tid & 63, w = tid >> 6;
  const int hi = lane >> 4, lo = lane & 15;
  const int bid = blockIdx.x;
  const int qt = bid & 15, bh = bid >> 4;
  const int qs = qt * 64 + w * 16;

  bf16x8 qf[2];
#pragma unroll
  for (int dh = 0; dh < 2; ++dh)
    qf[dh] = *(const bf16x8*)&Qb[((size_t)(bh << 10) + qs + lo) * 64 + dh * 32 + hi * 8];

  f32x4 acc[4];
  f32x4 sacc = (f32x4){0.f, 0.f, 0.f, 0.f};
  float mrun[4];
#pragma unroll
  for (int dt = 0; dt < 4; ++dt) acc[dt] = (f32x4){0.f, 0.f, 0.f, 0.f};
#pragma unroll
  for (int r = 0; r < 4; ++r) mrun[r] = -1e30f;
  bf16x8 ones;
#pragma unroll
  for (int j = 0; j < 8; ++j) ones[j] = (short)0x3F80;  // bf16 1.0

  for (int kt = 0; kt < 32; ++kt) {
    const int k0 = kt * 32;

    u32 keep[2][4];
#pragma unroll
    for (int t = 0; t < 2; ++t)
#pragma unroll
      for (int r = 0; r < 4; ++r) {
        const u32 j = ((u32)bh << 20) | ((u32)(qs + hi * 4 + r) << 10) | (u32)(k0 + t * 16 + lo);
        keep[t][r] = keep_bit(j);
      }

    // S = Q K^T over d=64 (two 16-key tiles)
    f32x4 st[2];
#pragma unroll
    for (int t = 0; t < 2; ++t) {
      const unsigned short* kbp = &Kb[((size_t)(bh << 10) + k0 + t * 16 + lo) * 64 + hi * 8];
      bf16x8 kf0 = *(const bf16x8*)kbp;
      bf16x8 kf1 = *(const bf16x8*)(kbp + 32);
      f32x4 z = (f32x4){0.f, 0.f, 0.f, 0.f};
      z = MFMA16(qf[0], kf0, z);
      z = MFMA16(qf[1], kf1, z);
      st[t] = z;
    }
    float sc[2][4];
#pragma unroll
    for (int t = 0; t < 2; ++t)
#pragma unroll
      for (int r = 0; r < 4; ++r)
        sc[t][r] = keep[t][r] ? st[t][r] * 0.125f : -1e30f;

    // row max across 16 key-col lanes (lo), rows indexed by (hi, r)
    float tm[4];
#pragma unroll
    for (int r = 0; r < 4; ++r) tm[r] = fmaxf(sc[0][r], sc[1][r]);
#pragma unroll
    for (int d = 1; d < 16; d <<= 1)
#pragma unroll
      for (int r = 0; r < 4; ++r) tm[r] = fmaxf(tm[r], __shfl_xor(tm[r], d));

    float ps[4];
#pragma unroll
    for (int r = 0; r < 4; ++r) {
      const float nm = fmaxf(mrun[r], tm[r]);
      ps[r] = __expf(mrun[r] - nm);
      mrun[r] = nm;
    }
#pragma unroll
    for (int dt = 0; dt < 4; ++dt)
#pragma unroll
      for (int r = 0; r < 4; ++r) acc[dt][r] *= ps[r];
#pragma unroll
    for (int r = 0; r < 4; ++r) sacc[r] *= ps[r];

    // P (bf16) -> LDS, D-layout write (row = hi*4+r, col = t*16+lo)
    unsigned short* mp = &plds[w][0];
#pragma unroll
    for (int t = 0; t < 2; ++t)
#pragma unroll
      for (int r = 0; r < 4; ++r) {
        const float p = keep[t][r] ? __expf(sc[t][r] - mrun[r]) : 0.f;
        mp[(hi * 4 + r) * 40 + t * 16 + lo] = f2bf(p);
      }

    asm volatile("s_waitcnt lgkmcnt(0)" ::: "memory");  // wave-private write->read

    bf16x8 pf = *(const bf16x8*)&mp[lo * 40 + hi * 8];  // A-frag: row lo, k = hi*8..+7
    sacc = MFMA16(pf, ones, sacc);                      // row-sums for free
#pragma unroll
    for (int dt = 0; dt < 4; ++dt) {
      bf16x8 vf = *(const bf16x8*)&VTb[((size_t)(bh * 64 + dt * 16 + lo)) * 1024 + k0 + hi * 8];
      acc[dt] = MFMA16(pf, vf, acc[dt]);
    }
    asm volatile("s_waitcnt lgkmcnt(0)" ::: "memory");  // reads done before next writes
  }

  // epilogue: normalize, write bf16 attn_out[token][h*64+d]
  const int b = bh >> 3, h = bh & 7;
#pragma unroll
  for (int r = 0; r < 4; ++r) {
    const float inv = 1.0f / sacc[r];
    const int tok = (b << 10) + qs + hi * 4 + r;
#pragma unroll
    for (int dt = 0; dt < 4; ++dt)
      aout[(size_t)tok * 512 + h * 64 + dt * 16 + lo] = f2bf(acc[dt][r] * inv);
  }
}

extern "C" void kernel_launch(void* const* d_in, const int* in_sizes, int n_in,
                              void* d_out, int out_size, void* d_ws, size_t ws_size,
                              hipStream_t stream) {
  const float* x      = (const float*)d_in[0];
  const float* qkv_w  = (const float*)d_in[1];
  const float* qkv_b  = (const float*)d_in[2];
  const float* proj_w = (const float*)d_in[3];
  const float* proj_b = (const float*)d_in[4];
  float* out = (float*)d_out;
  char* ws = (char*)d_ws;

  unsigned short* xb  = (unsigned short*)(ws);             // 8,388,608 (x bf16; reused as attn_out)
  unsigned short* qwb = (unsigned short*)(ws +  8388608);  // 1,572,864
  unsigned short* pwb = (unsigned short*)(ws +  9961472);  //   524,288
  unsigned short* Qb  = (unsigned short*)(ws + 10485760);  // 8,388,608 [bh][n][d]
  unsigned short* Kb  = (unsigned short*)(ws + 18874368);  // 8,388,608 [bh][n][d]
  unsigned short* VTb = (unsigned short*)(ws + 27262976);  // 8,388,608 [bh][d][n]

  cvt_kernel<<<5120, 256, 0, stream>>>(x, qkv_w, proj_w, xb, qwb, pwb);
  gemm_kernel<0><<<dim3(12, 64), 256, 0, stream>>>(xb, qwb, qkv_b, Qb, Kb, VTb, nullptr);
  attn_kernel<<<1024, 256, 0, stream>>>(Qb, Kb, VTb, xb);
  gemm_kernel<1><<<dim3(4, 64), 256, 0, stream>>>(xb, pwb, proj_b, nullptr, nullptr, nullptr, out);
}

// Round 5
// 210.917 us; speedup vs baseline: 1.1812x; 1.1812x over previous
//
#include <hip/hip_runtime.h>
#include <stdint.h>

typedef uint32_t u32;
using bf16x8 = __attribute__((ext_vector_type(8))) short;
using f32x4  = __attribute__((ext_vector_type(4))) float;

#define MFMA16(a, b, c) __builtin_amdgcn_mfma_f32_16x16x32_bf16((a), (b), (c), 0, 0, 0)

__device__ __forceinline__ unsigned short f2bf(float f) {
  u32 u = __builtin_bit_cast(u32, f);
  return (unsigned short)((u + 0x7FFFu + ((u >> 16) & 1u)) >> 16);  // RNE
}

__device__ __forceinline__ void gl_lds16(const unsigned short* g, unsigned short* l) {
  __builtin_amdgcn_global_load_lds((const __attribute__((address_space(1))) void*)g,
                                   (__attribute__((address_space(3))) void*)l, 16, 0, 0);
}

// ---------------- Threefry-2x32-20, key = (0, 42), single-instr rotates ----------------
__device__ __forceinline__ u32 rotl(u32 x, int r) {
  return __builtin_amdgcn_alignbit(x, x, 32 - r);  // v_alignbit_b32: rotr(x, 32-r) == rotl(x, r)
}
#define TFR(r) x0 += x1; x1 = rotl(x1, r) ^ x0;

// partitionable-threefry mask bit for flat index j (shape [8,8,1024,1024], j < 2^26):
// counter = (hi=0, lo=j); 32-bit word = o0 ^ o1; keep (mask=False) <=> MSB == 1.
__device__ __forceinline__ u32 keep_bit(u32 j) {
  const u32 ks1 = 42u, ks2 = 0x1BD11BDAu ^ 42u;
  u32 x0 = 0u;        // i0 = 0, ks0 = 0
  u32 x1 = j + ks1;
  TFR(13) TFR(15) TFR(26) TFR(6)
  x0 += ks1; x1 += ks2 + 1u;
  TFR(17) TFR(29) TFR(16) TFR(24)
  x0 += ks2; x1 += 0u + 2u;
  TFR(13) TFR(15) TFR(26) TFR(6)
  x0 += 0u; x1 += ks1 + 3u;
  TFR(17) TFR(29) TFR(16) TFR(24)
  x0 += ks1; x1 += ks2 + 4u;
  TFR(13) TFR(15) TFR(26) TFR(6)
  x0 += ks2; x1 += 0u + 5u;
  return (x0 ^ x1) >> 31;
}

// ---------------- fp32 -> bf16 conversion of x, qkv_w, proj_w ----------------
__global__ __launch_bounds__(256) void cvt_kernel(
    const float* __restrict__ x, const float* __restrict__ qw, const float* __restrict__ pw,
    unsigned short* __restrict__ xb, unsigned short* __restrict__ qwb,
    unsigned short* __restrict__ pwb) {
  int t = blockIdx.x * 256 + threadIdx.x;
  const float4* src; unsigned short* dst; int idx;
  if (t < 1048576)      { src = (const float4*)x;  dst = xb;  idx = t; }
  else if (t < 1245184) { src = (const float4*)qw; dst = qwb; idx = t - 1048576; }
  else                  { src = (const float4*)pw; dst = pwb; idx = t - 1245184; }
  float4 v = src[idx];
  ushort4 o = make_ushort4(f2bf(v.x), f2bf(v.y), f2bf(v.z), f2bf(v.w));
  ((ushort4*)dst)[idx] = o;
}

// ---------------- bf16 GEMM (m97 structure), C = A[M,512] * Bm[N,512]^T ----------
// EPI 0: qkv epilogue (+bias; Q pre-scaled by 0.125 (exact); scatter Q/K/VT bf16)
// EPI 1: proj epilogue (+bias, fp32 store)
template<int EPI>
__global__ __launch_bounds__(256)
void gemm_kernel(const unsigned short* __restrict__ A, const unsigned short* __restrict__ Bm,
                 const float* __restrict__ bias, unsigned short* __restrict__ q_out,
                 unsigned short* __restrict__ k_out, unsigned short* __restrict__ vt_out,
                 float* __restrict__ f_out) {
  __shared__ __align__(16) unsigned short lA[128 * 32];
  __shared__ __align__(16) unsigned short lB[128 * 32];
  const int tid = threadIdx.x;
  const int lane = tid & 63, w = tid >> 6;
  const int hi = lane >> 4, lo = lane & 15;
  const int wm = w >> 1, wn = w & 1;
  const int m0 = blockIdx.y * 128, n0 = blockIdx.x * 128;
  const int srow = lane >> 2, skc = (lane & 3) * 8;

  f32x4 acc[4][4];
#pragma unroll
  for (int i = 0; i < 4; ++i)
#pragma unroll
    for (int j = 0; j < 4; ++j) acc[i][j] = (f32x4){0.f, 0.f, 0.f, 0.f};

  for (int kt = 0; kt < 16; ++kt) {
    const int k0 = kt * 32;
    __syncthreads();
#pragma unroll
    for (int c = 0; c < 2; ++c) {
      const int rr = (w * 2 + c) * 16 + srow;
      gl_lds16(A  + (size_t)(m0 + rr) * 512 + k0 + skc, &lA[(w * 2 + c) * 512]);
      gl_lds16(Bm + (size_t)(n0 + rr) * 512 + k0 + skc, &lB[(w * 2 + c) * 512]);
    }
    __syncthreads();

    bf16x8 af[4], bfr[4];
#pragma unroll
    for (int i = 0; i < 4; ++i) af[i]  = *(const bf16x8*)&lA[(wm * 64 + i * 16 + lo) * 32 + hi * 8];
#pragma unroll
    for (int i = 0; i < 4; ++i) bfr[i] = *(const bf16x8*)&lB[(wn * 64 + i * 16 + lo) * 32 + hi * 8];
#pragma unroll
    for (int i = 0; i < 4; ++i)
#pragma unroll
      for (int j = 0; j < 4; ++j)
        acc[i][j] = MFMA16(af[i], bfr[j], acc[i][j]);
  }

  // C/D layout: col = lane&15, row = (lane>>4)*4 + reg  (m89/m91)
#pragma unroll
  for (int i = 0; i < 4; ++i) {
    const int rowb = m0 + wm * 64 + i * 16 + hi * 4;
#pragma unroll
    for (int j = 0; j < 4; ++j) {
      const int col = n0 + wn * 64 + j * 16 + lo;
      const float bv = bias[col];
      if (EPI == 0) {
        const int which = col >> 9, hh = (col >> 6) & 7, dd = col & 63;
        const float scl = (which == 0) ? 0.125f : 1.0f;  // fold softmax SCALE into Q (exact)
#pragma unroll
        for (int r = 0; r < 4; ++r) {
          const int tok = rowb + r;
          const int b = tok >> 10, nt = tok & 1023;
          const int bh = b * 8 + hh;
          const unsigned short val = f2bf((acc[i][j][r] + bv) * scl);
          if (which == 0)      q_out[((size_t)((bh << 10) + nt)) * 64 + dd] = val;
          else if (which == 1) k_out[((size_t)((bh << 10) + nt)) * 64 + dd] = val;
          else                 vt_out[((size_t)bh * 64 + dd) * 1024 + nt] = val;
        }
      } else {
#pragma unroll
        for (int r = 0; r < 4; ++r)
          f_out[(size_t)(rowb + r) * 512 + col] = acc[i][j][r] + bv;
      }
    }
  }
}

// ---------------- fused flash attention + partitionable-threefry mask, KVBLK=64 ----------------
// Grid 1024 = bh(64) x qtile(16). Block = 4 waves; wave w owns 16 q-rows.
// Per 64-key iter: 16 threefry/lane, 4x2 QK^T MFMA (Q pre-scaled), online softmax,
// P->LDS relayout (stride 68 shorts: conflict-free), ones-MFMA row-sum, 8 PV MFMA.
__global__ __launch_bounds__(256, 4) void attn_kernel(
    const unsigned short* __restrict__ Qb, const unsigned short* __restrict__ Kb,
    const unsigned short* __restrict__ VTb, unsigned short* __restrict__ aout) {
  __shared__ __align__(16) unsigned short plds[4][16 * 68];  // per-wave, 136B row stride
  const int tid = threadIdx.x;
  const int lane = tid & 63, w = tid >> 6;
  const int hi = lane >> 4, lo = lane & 15;
  const int bid = blockIdx.x;
  const int qt = bid & 15, bh = bid >> 4;
  const int qs = qt * 64 + w * 16;

  bf16x8 qf[2];
#pragma unroll
  for (int dh = 0; dh < 2; ++dh)
    qf[dh] = *(const bf16x8*)&Qb[((size_t)(bh << 10) + qs + lo) * 64 + dh * 32 + hi * 8];

  f32x4 acc[4];
  f32x4 sacc = (f32x4){0.f, 0.f, 0.f, 0.f};
  float mrun[4];
#pragma unroll
  for (int dt = 0; dt < 4; ++dt) acc[dt] = (f32x4){0.f, 0.f, 0.f, 0.f};
#pragma unroll
  for (int r = 0; r < 4; ++r) mrun[r] = -1e30f;
  bf16x8 ones;
#pragma unroll
  for (int j = 0; j < 8; ++j) ones[j] = (short)0x3F80;  // bf16 1.0

  const u32 jbase = ((u32)bh << 20) | ((u32)(qs + hi * 4) << 10) | (u32)lo;

  for (int kt = 0; kt < 16; ++kt) {
    const int k0 = kt * 64;

    // mask bits (16 threefry/lane)
    u32 keep[4][4];
#pragma unroll
    for (int t = 0; t < 4; ++t)
#pragma unroll
      for (int r = 0; r < 4; ++r)
        keep[t][r] = keep_bit(jbase + ((u32)r << 10) + (u32)(k0 + t * 16));

    // S = Q K^T over d=64, four 16-key tiles (Q pre-scaled by 0.125)
    float sc[4][4];
#pragma unroll
    for (int t = 0; t < 4; ++t) {
      const unsigned short* kbp = &Kb[((size_t)(bh << 10) + k0 + t * 16 + lo) * 64 + hi * 8];
      bf16x8 kf0 = *(const bf16x8*)kbp;
      bf16x8 kf1 = *(const bf16x8*)(kbp + 32);
      f32x4 z = (f32x4){0.f, 0.f, 0.f, 0.f};
      z = MFMA16(qf[0], kf0, z);
      z = MFMA16(qf[1], kf1, z);
#pragma unroll
      for (int r = 0; r < 4; ++r) sc[t][r] = keep[t][r] ? z[r] : -1e30f;
    }

    // row max across 16 key-col lanes (lo); rows indexed by (hi, r)
    float tm[4];
#pragma unroll
    for (int r = 0; r < 4; ++r)
      tm[r] = fmaxf(fmaxf(sc[0][r], sc[1][r]), fmaxf(sc[2][r], sc[3][r]));
#pragma unroll
    for (int d = 1; d < 16; d <<= 1)
#pragma unroll
      for (int r = 0; r < 4; ++r) tm[r] = fmaxf(tm[r], __shfl_xor(tm[r], d));

    float ps[4];
#pragma unroll
    for (int r = 0; r < 4; ++r) {
      const float nm = fmaxf(mrun[r], tm[r]);
      ps[r] = __expf(mrun[r] - nm);
      mrun[r] = nm;
    }
#pragma unroll
    for (int dt = 0; dt < 4; ++dt)
#pragma unroll
      for (int r = 0; r < 4; ++r) acc[dt][r] *= ps[r];
#pragma unroll
    for (int r = 0; r < 4; ++r) sacc[r] *= ps[r];

    // P (bf16) -> LDS, D-layout write (row = hi*4+r, col = t*16+lo).
    // masked sc = -1e30 -> exp underflows to exactly 0 (all-64-masked tile prob ~2^-64).
    unsigned short* mp = &plds[w][0];
#pragma unroll
    for (int t = 0; t < 4; ++t)
#pragma unroll
      for (int r = 0; r < 4; ++r)
        mp[(hi * 4 + r) * 68 + t * 16 + lo] = f2bf(__expf(sc[t][r] - mrun[r]));

    asm volatile("s_waitcnt lgkmcnt(0)" ::: "memory");  // wave-private write->read RAW

    bf16x8 pf[2];
#pragma unroll
    for (int ks = 0; ks < 2; ++ks)
      pf[ks] = *(const bf16x8*)&mp[lo * 68 + ks * 32 + hi * 8];  // A-frag row lo, k=ks*32+hi*8..+7
    sacc = MFMA16(pf[0], ones, sacc);
    sacc = MFMA16(pf[1], ones, sacc);
#pragma unroll
    for (int dt = 0; dt < 4; ++dt) {
      const unsigned short* vbp = &VTb[((size_t)(bh * 64 + dt * 16 + lo)) * 1024 + k0 + hi * 8];
      acc[dt] = MFMA16(pf[0], *(const bf16x8*)vbp, acc[dt]);
      acc[dt] = MFMA16(pf[1], *(const bf16x8*)(vbp + 32), acc[dt]);
    }
    // WAR to next iter's LDS writes is safe: per-wave in-order DS pipe + compiler alias order.
  }

  // epilogue: normalize, write bf16 attn_out[token][h*64+d]
  const int b = bh >> 3, h = bh & 7;
#pragma unroll
  for (int r = 0; r < 4; ++r) {
    const float inv = 1.0f / sacc[r];
    const int tok = (b << 10) + qs + hi * 4 + r;
#pragma unroll
    for (int dt = 0; dt < 4; ++dt)
      aout[(size_t)tok * 512 + h * 64 + dt * 16 + lo] = f2bf(acc[dt][r] * inv);
  }
}

extern "C" void kernel_launch(void* const* d_in, const int* in_sizes, int n_in,
                              void* d_out, int out_size, void* d_ws, size_t ws_size,
                              hipStream_t stream) {
  const float* x      = (const float*)d_in[0];
  const float* qkv_w  = (const float*)d_in[1];
  const float* qkv_b  = (const float*)d_in[2];
  const float* proj_w = (const float*)d_in[3];
  const float* proj_b = (const float*)d_in[4];
  float* out = (float*)d_out;
  char* ws = (char*)d_ws;

  unsigned short* xb  = (unsigned short*)(ws);             // 8,388,608 (x bf16; reused as attn_out)
  unsigned short* qwb = (unsigned short*)(ws +  8388608);  // 1,572,864
  unsigned short* pwb = (unsigned short*)(ws +  9961472);  //   524,288
  unsigned short* Qb  = (unsigned short*)(ws + 10485760);  // 8,388,608 [bh][n][d], pre-scaled 0.125
  unsigned short* Kb  = (unsigned short*)(ws + 18874368);  // 8,388,608 [bh][n][d]
  unsigned short* VTb = (unsigned short*)(ws + 27262976);  // 8,388,608 [bh][d][n]

  cvt_kernel<<<5120, 256, 0, stream>>>(x, qkv_w, proj_w, xb, qwb, pwb);
  gemm_kernel<0><<<dim3(12, 64), 256, 0, stream>>>(xb, qwb, qkv_b, Qb, Kb, VTb, nullptr);
  attn_kernel<<<1024, 256, 0, stream>>>(Qb, Kb, VTb, xb);
  gemm_kernel<1><<<dim3(4, 64), 256, 0, stream>>>(xb, pwb, proj_b, nullptr, nullptr, nullptr, out);
}